// Round 1
// baseline (494.293 us; speedup 1.0000x reference)
//
#include <hip/hip_runtime.h>
#include <hip/hip_bf16.h>

#define B_ROWS 32768
#define NBLK 12

typedef __attribute__((ext_vector_type(8)))  short        s8v;   // 8 x bf16 (4 VGPR)
typedef __attribute__((ext_vector_type(4)))  float        f4v;   // 4 x f32
typedef __attribute__((ext_vector_type(4)))  unsigned int u4v;   // 16B copy

__device__ __forceinline__ short f2bf(float f){            // f32 -> bf16 RNE
  unsigned u = __builtin_bit_cast(unsigned, f);
  u = (u + 0x7fffu + ((u >> 16) & 1u)) >> 16;
  return (short)u;
}

// ---------------- LDS layout (bytes) ----------------
#define OXIN  0        // bf16 [128][168]  (cols 0..31 = x-half, 32..159 = H, pad 8)
#define XIN_S 168
#define OXF   43008    // f32  [128][64]   x (persistent across blocks)
#define OHC   75776    // bf16 [128][72]   hidden chunk (pad 8)
#define HC_S  72
#define OWB   94208    // 2 bufs x 30720: W1c bf16[64][168] (21504) + W2c bf16[64][72] (9216)
#define W1_S  168
#define W2_S  72
#define WBUF_SZ 30720
#define ORB   94208    // f32 [128][66] alias over weight bufs (r output)
#define RB_S  66
#define OLJ   155648   // f32[128] per-row logj accumulator
#define OPERM 156160   // int[64]
#define OELS  156416   // f32[64] exp(logscale)
#define OBIV  156672   // f32[64] bias
#define OSLS  156928   // f32 scalar: sum of all an_logscale
#define SM_SZ 156944

// ws (bf16 weights) element offsets
#define O_S1W1 0
#define O_S1W2 983040
#define O_S2W1 1376256
#define O_S2W2 2359296
#define W_TOTAL 2752512

// -------- one-time f32 -> bf16 weight conversion --------
__global__ void cvtw(const float* __restrict__ s1w1, const float* __restrict__ s1w2,
                     const float* __restrict__ s2w1, const float* __restrict__ s2w2,
                     unsigned short* __restrict__ dst)
{
  long t = (long)blockIdx.x * blockDim.x + threadIdx.x;
  if (t >= W_TOTAL) return;
  float v;
  if      (t < O_S1W2) v = s1w1[t];
  else if (t < O_S2W1) v = s1w2[t - O_S1W2];
  else if (t < O_S2W2) v = s2w1[t - O_S2W1];
  else                 v = s2w2[t - O_S2W2];
  dst[t] = (unsigned short)f2bf(v);
}

// -------- stage one 64-unit hidden chunk of W1/W2 into LDS buffer --------
__device__ __forceinline__ void stage_chunk(char* sm, int tid, int c, int buf,
    const unsigned short* w1bf, const unsigned short* w2bf,
    const float* w1f, const float* w2f, int usebf)
{
  short* W1d = (short*)(sm + OWB + buf * WBUF_SZ);
  short* W2d = (short*)(sm + OWB + buf * WBUF_SZ + 21504);
  if (usebf){
    const unsigned short* s1 = w1bf + (size_t)c * (64 * 160);
    #pragma unroll
    for (int t = 0; t < 3; ++t){
      int i = tid + t * 512;
      if (i < 1280){                       // 64*160/8 16B chunks
        int row = i / 20, col = i - row * 20;
        u4v v = *(const u4v*)(s1 + (size_t)i * 8);
        *(u4v*)(W1d + row * W1_S + col * 8) = v;
      }
    }
    const unsigned short* s2 = w2bf + (size_t)c * 64;     // row stride 512
    { int row = tid >> 3, col8 = tid & 7;
      u4v v = *(const u4v*)(s2 + (size_t)row * 512 + col8 * 8);
      *(u4v*)(W2d + row * W2_S + col8 * 8) = v; }
  } else {
    const float* s1 = w1f + (size_t)c * (64 * 160);
    #pragma unroll
    for (int t = 0; t < 3; ++t){
      int i = tid + t * 512;
      if (i < 1280){
        int row = i / 20, col = i - row * 20;
        f4v a = *(const f4v*)(s1 + (size_t)i * 8);
        f4v b = *(const f4v*)(s1 + (size_t)i * 8 + 4);
        s8v pv;
        pv[0]=f2bf(a[0]); pv[1]=f2bf(a[1]); pv[2]=f2bf(a[2]); pv[3]=f2bf(a[3]);
        pv[4]=f2bf(b[0]); pv[5]=f2bf(b[1]); pv[6]=f2bf(b[2]); pv[7]=f2bf(b[3]);
        *(s8v*)(W1d + row * W1_S + col * 8) = pv;
      }
    }
    const float* s2 = w2f + (size_t)c * 64;
    { int row = tid >> 3, col8 = tid & 7;
      f4v a = *(const f4v*)(s2 + (size_t)row * 512 + col8 * 8);
      f4v b = *(const f4v*)(s2 + (size_t)row * 512 + col8 * 8 + 4);
      s8v pv;
      pv[0]=f2bf(a[0]); pv[1]=f2bf(a[1]); pv[2]=f2bf(a[2]); pv[3]=f2bf(a[3]);
      pv[4]=f2bf(b[0]); pv[5]=f2bf(b[1]); pv[6]=f2bf(b[2]); pv[7]=f2bf(b[3]);
      *(s8v*)(W2d + row * W2_S + col8 * 8) = pv; }
  }
}

// -------- one MLP + coupling update.  TGT: which x-half gets updated (0 or 32) --------
template<int TGT>
__device__ __forceinline__ void mlp_pass(char* sm, int tid,
    const unsigned short* w1bf, const unsigned short* w2bf,
    const float* w1f, const float* w2f,
    const float* b1p, const float* b2p, int usebf)
{
  const int lane = tid & 63, wave = tid >> 6;
  const int wm = wave >> 1, wn = wave & 1;         // 4 x 2 wave grid, 32x32 tiles
  const int l15 = lane & 15, lq = lane >> 4;       // lq in 0..3
  short* XIN = (short*)(sm + OXIN);
  short* HCb = (short*)(sm + OHC);
  float* XF  = (float*)(sm + OXF);
  float* RB  = (float*)(sm + ORB);
  float* LOGJ= (float*)(sm + OLJ);

  // A fragments (input rows), register-resident for the whole MLP
  s8v afr[2][5];
  #pragma unroll
  for (int tm = 0; tm < 2; ++tm){
    int ar = wm * 32 + tm * 16 + l15;
    #pragma unroll
    for (int kk = 0; kk < 5; ++kk)
      afr[tm][kk] = *(const s8v*)(XIN + ar * XIN_S + kk * 32 + lq * 8);
  }

  f4v zz = {0.f, 0.f, 0.f, 0.f};
  f4v racc[2][2] = {{zz, zz}, {zz, zz}};

  stage_chunk(sm, tid, 0, 0, w1bf, w2bf, w1f, w2f, usebf);
  __syncthreads();

  for (int c = 0; c < 8; ++c){
    int buf = c & 1;
    if (c < 7) stage_chunk(sm, tid, c + 1, buf ^ 1, w1bf, w2bf, w1f, w2f, usebf);
    short* W1c = (short*)(sm + OWB + buf * WBUF_SZ);
    short* W2c = (short*)(sm + OWB + buf * WBUF_SZ + 21504);

    // GEMM1: (128x160) @ (160x64 chunk) -> hidden
    f4v acc[2][2] = {{zz, zz}, {zz, zz}};
    #pragma unroll
    for (int kk = 0; kk < 5; ++kk){
      s8v b0 = *(const s8v*)(W1c + (wn * 32 +  0 + l15) * W1_S + kk * 32 + lq * 8);
      s8v b1 = *(const s8v*)(W1c + (wn * 32 + 16 + l15) * W1_S + kk * 32 + lq * 8);
      #pragma unroll
      for (int tm = 0; tm < 2; ++tm){
        acc[tm][0] = __builtin_amdgcn_mfma_f32_16x16x32_bf16(afr[tm][kk], b0, acc[tm][0], 0, 0, 0);
        acc[tm][1] = __builtin_amdgcn_mfma_f32_16x16x32_bf16(afr[tm][kk], b1, acc[tm][1], 0, 0, 0);
      }
    }
    float bia0 = b1p[c * 64 + wn * 32 + l15];
    float bia1 = b1p[c * 64 + wn * 32 + 16 + l15];
    #pragma unroll
    for (int tm = 0; tm < 2; ++tm)
      #pragma unroll
      for (int tn = 0; tn < 2; ++tn){
        int colh = wn * 32 + tn * 16 + l15;
        float bb = tn ? bia1 : bia0;
        #pragma unroll
        for (int r = 0; r < 4; ++r){
          int rowh = wm * 32 + tm * 16 + lq * 4 + r;
          float hv = acc[tm][tn][r] + bb;
          hv = hv > 0.f ? hv : 0.f;
          HCb[rowh * HC_S + colh] = f2bf(hv);
        }
      }
    __syncthreads();

    // GEMM2: (128x64 chunk) @ (64x64) accumulate r
    #pragma unroll
    for (int kk = 0; kk < 2; ++kk){
      s8v a20 = *(const s8v*)(HCb + (wm * 32 +  0 + l15) * HC_S + kk * 32 + lq * 8);
      s8v a21 = *(const s8v*)(HCb + (wm * 32 + 16 + l15) * HC_S + kk * 32 + lq * 8);
      s8v b20 = *(const s8v*)(W2c + (wn * 32 +  0 + l15) * W2_S + kk * 32 + lq * 8);
      s8v b21 = *(const s8v*)(W2c + (wn * 32 + 16 + l15) * W2_S + kk * 32 + lq * 8);
      racc[0][0] = __builtin_amdgcn_mfma_f32_16x16x32_bf16(a20, b20, racc[0][0], 0, 0, 0);
      racc[0][1] = __builtin_amdgcn_mfma_f32_16x16x32_bf16(a20, b21, racc[0][1], 0, 0, 0);
      racc[1][0] = __builtin_amdgcn_mfma_f32_16x16x32_bf16(a21, b20, racc[1][0], 0, 0, 0);
      racc[1][1] = __builtin_amdgcn_mfma_f32_16x16x32_bf16(a21, b21, racc[1][1], 0, 0, 0);
    }
    __syncthreads();
  }

  // write r (+bias2) to RB (aliases weight bufs; all reads done)
  float bo0 = b2p[wn * 32 + l15];
  float bo1 = b2p[wn * 32 + 16 + l15];
  #pragma unroll
  for (int tm = 0; tm < 2; ++tm)
    #pragma unroll
    for (int tn = 0; tn < 2; ++tn){
      int col = wn * 32 + tn * 16 + l15;
      float bb = tn ? bo1 : bo0;
      #pragma unroll
      for (int r = 0; r < 4; ++r){
        int row = wm * 32 + tm * 16 + lq * 4 + r;
        RB[row * RB_S + col] = racc[tm][tn][r] + bb;
      }
    }
  __syncthreads();

  // coupling: y = exp(le)*x_half + r_add ;  logj += sum(le)
  {
    int rr = tid >> 2, g = tid & 3;
    float part = 0.f;
    #pragma unroll
    for (int j = 0; j < 8; ++j){
      int cc = g * 8 + j;
      float rA  = RB[rr * RB_S + cc];
      float rBv = RB[rr * RB_S + 32 + cc];
      float le = 0.636f * atanf(rA);
      float y  = __expf(le) * XF[rr * 64 + TGT + cc] + rBv;
      XF[rr * 64 + TGT + cc] = y;
      if (TGT == 0) XIN[rr * XIN_S + cc] = f2bf(y);   // y1 feeds MLP1 input
      part += le;
    }
    part += __shfl_xor(part, 1);
    part += __shfl_xor(part, 2);
    if (g == 0) LOGJ[rr] += part;
  }
  __syncthreads();
}

__global__ __launch_bounds__(512, 2) void cinn_main(
    const float* __restrict__ q, const float* __restrict__ Hg,
    const int* __restrict__ perms,
    const float* __restrict__ ls_g, const float* __restrict__ bi_g,
    const float* __restrict__ s1b1, const float* __restrict__ s1b2,
    const float* __restrict__ s2b1, const float* __restrict__ s2b2,
    const unsigned short* __restrict__ wbf,
    const float* __restrict__ s1W1f, const float* __restrict__ s1W2f,
    const float* __restrict__ s2W1f, const float* __restrict__ s2W2f,
    int usebf, float* __restrict__ outz, float* __restrict__ outlj)
{
  __shared__ __align__(16) char sm[SM_SZ];
  const int tid = threadIdx.x;
  const int rowbase = blockIdx.x * 128;

  short* XIN = (short*)(sm + OXIN);
  float* XF  = (float*)(sm + OXF);
  float* LOGJ= (float*)(sm + OLJ);
  int*   PERM= (int*)(sm + OPERM);
  float* ELS = (float*)(sm + OELS);
  float* BIV = (float*)(sm + OBIV);
  float* SLSp= (float*)(sm + OSLS);

  // init x and H-part of MLP input
  for (int i = tid; i < 128 * 64; i += 512){
    int r = i >> 6, c = i & 63;
    XF[r * 64 + c] = q[(size_t)(rowbase + r) * 64 + c];
  }
  for (int i = tid; i < 128 * 128; i += 512){
    int r = i >> 7, c = i & 127;
    XIN[r * XIN_S + 32 + c] = f2bf(Hg[(size_t)(rowbase + r) * 128 + c]);
  }
  if (tid < 128) LOGJ[tid] = 0.f;
  if (tid == 0)  *SLSp = 0.f;
  __syncthreads();
  if (tid < 64){
    float p = 0.f;
    for (int k = 0; k < NBLK; ++k) p += ls_g[k * 64 + tid];
    atomicAdd(SLSp, p);
  }

  for (int blk = 0; blk < NBLK; ++blk){
    if (tid < 64){
      PERM[tid] = perms[blk * 64 + tid];
      ELS[tid]  = __expf(ls_g[blk * 64 + tid]);
      BIV[tid]  = bi_g[blk * 64 + tid];
    }
    __syncthreads();

    // permute + affine (in place on XF; read-all then write-all)
    {
      int r = tid >> 2, g = tid & 3;
      float v[16];
      #pragma unroll
      for (int j = 0; j < 16; ++j) v[j] = XF[r * 64 + PERM[g * 16 + j]];
      __syncthreads();
      #pragma unroll
      for (int j = 0; j < 16; ++j){
        int i = g * 16 + j;
        float nv = v[j] * ELS[i] + BIV[i];
        XF[r * 64 + i] = nv;
        if (i >= 32) XIN[r * XIN_S + (i - 32)] = f2bf(nv);  // x2 -> MLP2 input
      }
    }
    __syncthreads();

    // MLP2 (s2 weights): r2 = mlp([x2,H]); y1 = exp(le2)*x1 + r2b  -> cols 0..31
    mlp_pass<0>(sm, tid,
        wbf + O_S2W1 + (size_t)blk * 81920, wbf + O_S2W2 + (size_t)blk * 32768,
        s2W1f + (size_t)blk * 81920, s2W2f + (size_t)blk * 32768,
        s2b1 + blk * 512, s2b2 + blk * 64, usebf);

    // MLP1 (s1 weights): r1 = mlp([y1,H]); y2 = exp(le1)*x2 + r1b  -> cols 32..63
    mlp_pass<32>(sm, tid,
        wbf + O_S1W1 + (size_t)blk * 81920, wbf + O_S1W2 + (size_t)blk * 32768,
        s1W1f + (size_t)blk * 81920, s1W2f + (size_t)blk * 32768,
        s1b1 + blk * 512, s1b2 + blk * 64, usebf);
  }

  for (int i = tid; i < 128 * 64; i += 512){
    int r = i >> 6, c = i & 63;
    outz[(size_t)(rowbase + r) * 64 + c] = XF[r * 64 + c];
  }
  if (tid < 128) outlj[rowbase + tid] = LOGJ[tid] + *SLSp;
}

extern "C" void kernel_launch(void* const* d_in, const int* in_sizes, int n_in,
                              void* d_out, int out_size, void* d_ws, size_t ws_size,
                              hipStream_t stream)
{
  const float* q    = (const float*)d_in[0];
  const float* Hg   = (const float*)d_in[1];
  const int*   perms= (const int*)  d_in[2];
  const float* ls   = (const float*)d_in[3];
  const float* bi   = (const float*)d_in[4];
  const float* s1W1 = (const float*)d_in[5];
  const float* s1b1 = (const float*)d_in[6];
  const float* s1W2 = (const float*)d_in[7];
  const float* s1b2 = (const float*)d_in[8];
  const float* s2W1 = (const float*)d_in[9];
  const float* s2b1 = (const float*)d_in[10];
  const float* s2W2 = (const float*)d_in[11];
  const float* s2b2 = (const float*)d_in[12];
  float* outz  = (float*)d_out;
  float* outlj = outz + (size_t)B_ROWS * 64;

  int usebf = (ws_size >= (size_t)W_TOTAL * 2) ? 1 : 0;
  unsigned short* wbf = (unsigned short*)d_ws;
  if (usebf)
    cvtw<<<2688, 1024, 0, stream>>>(s1W1, s1W2, s2W1, s2W2, wbf);

  cinn_main<<<256, 512, 0, stream>>>(q, Hg, perms, ls, bi,
                                     s1b1, s1b2, s2b1, s2b2,
                                     wbf, s1W1, s1W2, s2W1, s2W2,
                                     usebf, outz, outlj);
}